// Round 1
// baseline (1467.444 us; speedup 1.0000x reference)
//
#include <hip/hip_runtime.h>
#include <cmath>

// ---------------- problem constants ----------------
#define SNUM 6
#define CNUM 128
#define HF 56
#define WF 100
#define HW (HF*WF)          // 5600
#define ZN 128
#define YN 8
#define XN 128
#define NVOX (ZN*YN*XN)     // 131072

// ---------------- setup: per-camera matrices ----------------
// mats[s*24 + 0..11]  = camXs_T_cam0 rows 0..2 (row-major 3x4)
// mats[s*24 + 12..23] = pixB_T_cam0 rows 0..2
__global__ void k_setup(const float* __restrict__ intrins,
                        const float* __restrict__ rots,
                        const float* __restrict__ trans,
                        float* __restrict__ mats) {
    int s = threadIdx.x;
    if (s >= SNUM) return;
    float R0[9], Rs[9], t0[3], ts[3];
    for (int i = 0; i < 9; ++i) { R0[i] = rots[i]; Rs[i] = rots[s*9 + i]; }
    for (int i = 0; i < 3; ++i) { t0[i] = trans[i]; ts[i] = trans[s*3 + i]; }
    // M = [Rs^T R0 | Rs^T (t0 - ts)]
    float M[3][4];
    float d0 = t0[0]-ts[0], d1 = t0[1]-ts[1], d2 = t0[2]-ts[2];
    for (int i = 0; i < 3; ++i) {
        for (int j = 0; j < 3; ++j)
            M[i][j] = Rs[0*3+i]*R0[0*3+j] + Rs[1*3+i]*R0[1*3+j] + Rs[2*3+i]*R0[2*3+j];
        M[i][3] = Rs[0*3+i]*d0 + Rs[1*3+i]*d1 + Rs[2*3+i]*d2;
    }
    const float sx = (float)WF/800.0f, sy = (float)HF/448.0f;
    float fx = intrins[s*16 + 0]*sx, fy = intrins[s*16 + 5]*sy;
    float cx = intrins[s*16 + 2]*sx, cy = intrins[s*16 + 6]*sy;
    float* o = mats + s*24;
    for (int j = 0; j < 4; ++j) {
        o[0*4+j]      = M[0][j];
        o[1*4+j]      = M[1][j];
        o[2*4+j]      = M[2][j];
        o[12 + 0*4+j] = fx*M[0][j] + cx*M[2][j];
        o[12 + 1*4+j] = fy*M[1][j] + cy*M[2][j];
        o[12 + 2*4+j] = M[2][j];
    }
}

// ---------------- transpose cam_feat (S,C,HW) -> featT (S,HW,C) ----------------
__global__ __launch_bounds__(256) void k_tfeat(const float* __restrict__ cf,
                                               float* __restrict__ featT) {
    __shared__ float t[32][33];
    int s = blockIdx.z;
    int p0 = blockIdx.x * 32, c0 = blockIdx.y * 32;
    int tx = threadIdx.x, ty = threadIdx.y;   // 32 x 8
#pragma unroll
    for (int k = 0; k < 4; ++k) {
        int r = ty + k*8;
        t[r][tx] = cf[((size_t)s*CNUM + c0 + r)*HW + p0 + tx];
    }
    __syncthreads();
#pragma unroll
    for (int k = 0; k < 4; ++k) {
        int r = ty + k*8;
        featT[((size_t)s*HW + p0 + r)*CNUM + c0 + tx] = t[tx][r];
    }
}

// ---------------- per-voxel projection -> (ux,uy) per camera ----------------
__global__ __launch_bounds__(256) void k_geo(const float* __restrict__ mats,
                                             float* __restrict__ uv) {
#pragma clang fp contract(off)
    int n = blockIdx.x * 256 + threadIdx.x;
    int zi = n >> 10, yi = (n >> 7) & 7, xi = n & 127;
    float xr = -49.609375f + (float)xi * 0.78125f;   // xmin + vsx/2 + xi*vsx
    float yr = (-4.9f + 0.625f) + (float)yi * 1.25f;
    float zr = -49.609375f + (float)zi * 0.78125f;
#pragma unroll
    for (int s = 0; s < SNUM; ++s) {
        const float* m = mats + s*24;
        float zc = m[8]*xr  + m[9]*yr  + m[10]*zr + m[11];
        float ph = m[12]*xr + m[13]*yr + m[14]*zr + m[15];
        float qh = m[16]*xr + m[17]*yr + m[18]*zr + m[19];
        float denom = fmaxf(zc, 1e-6f);
        float px = ph / denom, py = qh / denom;
        bool valid = (px > -0.5f) & (px < (float)WF - 0.5f) &
                     (py > -0.5f) & (py < (float)HF - 0.5f) & (zc > 0.0f);
        float ux = -10000.0f, uy = -10000.0f;
        if (valid) {
            float gx = 2.0f*px/((float)WF - 1.0f) - 1.0f;
            float gy = 2.0f*py/((float)HF - 1.0f) - 1.0f;
            gx = fminf(fmaxf(gx, -2.0f), 2.0f);
            gy = fminf(fmaxf(gy, -2.0f), 2.0f);
            ux = ((gx + 1.0f)*(float)WF - 1.0f)*0.5f;
            uy = ((gy + 1.0f)*(float)HF - 1.0f)*0.5f;
        }
        uv[(n*SNUM + s)*2]     = ux;
        uv[(n*SNUM + s)*2 + 1] = uy;
    }
}

// ---------------- bilinear sample + masked camera mean ----------------
// block = 256 thr = 16 voxels (same z,y; consecutive x) x 16 channel lanes,
// each thread does 8 channel groups. LDS exchange -> coalesced (c*8+y,z,x) writes.
__global__ __launch_bounds__(256) void k_sample(const float* __restrict__ featT,
                                                const float* __restrict__ uv,
                                                float* __restrict__ bevin) {
#pragma clang fp contract(off)
    __shared__ float xch[16*132];
    const int tid = threadIdx.x;
    const int b = blockIdx.x;           // 8192 blocks
    const int zy = b >> 3;
    const int x0 = (b & 7) * 16;
    const int z = zy >> 3, y = zy & 7;
    const int n0 = zy * 128 + x0;
    const int cl = tid & 15, vx = tid >> 4;
    const int n = n0 + vx;
    float sum[8], cnt[8];
#pragma unroll
    for (int k = 0; k < 8; ++k) { sum[k] = 0.0f; cnt[k] = 0.0f; }
    for (int s = 0; s < SNUM; ++s) {
        float2 u = ((const float2*)uv)[n*SNUM + s];
        if (u.x < -999.0f) continue;   // invalid camera for this voxel
        float x0f = floorf(u.x), y0f = floorf(u.y);
        float wx = u.x - x0f, wy = u.y - y0f;
        int ix = (int)x0f, iy = (int)y0f;
        float w00 = (1.0f-wx)*(1.0f-wy), w10 = wx*(1.0f-wy);
        float w01 = (1.0f-wx)*wy,        w11 = wx*wy;
        bool bx0 = (ix >= 0) & (ix < WF);
        bool bx1 = (ix >= -1) & (ix < WF-1);
        bool by0 = (iy >= 0) & (iy < HF);
        bool by1 = (iy >= -1) & (iy < HF-1);
        bool c00 = bx0 & by0, c10 = bx1 & by0, c01 = bx0 & by1, c11 = bx1 & by1;
        const float* fb = featT + (size_t)s * (HW*CNUM) + cl;
        long r0 = (long)(iy*WF + ix) * CNUM;
#pragma unroll
        for (int k = 0; k < 8; ++k) {
            int co = k*16;
            float v = 0.0f;
            if (c00) v = v + w00 * fb[r0 + co];
            if (c10) v = v + w10 * fb[r0 + co + CNUM];
            if (c01) v = v + w01 * fb[r0 + co + WF*CNUM];
            if (c11) v = v + w11 * fb[r0 + co + WF*CNUM + CNUM];
            sum[k] += v;
            cnt[k] += (v != 0.0f) ? 1.0f : 0.0f;
        }
    }
#pragma unroll
    for (int k = 0; k < 8; ++k)
        xch[vx*132 + k*16 + cl] = sum[k] / (1e-6f + cnt[k]);
    __syncthreads();
#pragma unroll
    for (int k = 0; k < 8; ++k) {
        int co = k*16 + vx;     // channel
        bevin[(size_t)(co*YN + y)*(ZN*XN) + z*XN + x0 + cl] = xch[cl*132 + co];
    }
}

// ---------------- direct conv 3x3: (1024,128,128) -> (128,128,128) ----------------
// block: 16 c_out x 2 z rows x 128 x. Weights read via block-uniform (scalar) loads.
__global__ __launch_bounds__(256) void k_conv(const float* __restrict__ bevin,
                                              const float* __restrict__ w,
                                              float* __restrict__ out) {
    __shared__ float smem[4][130];
    const int tid = threadIdx.x;
    const int x = tid & 127, zh = tid >> 7;
    const int co0 = blockIdx.x * 16;
    const int z0 = blockIdx.y * 2;
    if (tid < 8) smem[tid >> 1][(tid & 1) * 129] = 0.0f;
    float acc[16];
#pragma unroll
    for (int i = 0; i < 16; ++i) acc[i] = 0.0f;
    for (int ci = 0; ci < 1024; ++ci) {
        __syncthreads();
#pragma unroll
        for (int k = 0; k < 2; ++k) {
            int idx = tid + k*256;
            int r = idx >> 7, xx = idx & 127;
            int zr = z0 - 1 + r;
            float v = (zr >= 0 && zr < 128) ? bevin[(size_t)ci*16384 + zr*128 + xx] : 0.0f;
            smem[r][1+xx] = v;
        }
        __syncthreads();
        float iv[9];
#pragma unroll
        for (int r = 0; r < 3; ++r)
#pragma unroll
            for (int d = 0; d < 3; ++d)
                iv[r*3+d] = smem[zh + r][x + d];
        const float* wb = w + (size_t)co0*9216 + ci*9;
#pragma unroll
        for (int co = 0; co < 16; ++co) {
            const float* wp = wb + (size_t)co*9216;  // block-uniform -> s_load
            float a = acc[co];
            a += wp[0]*iv[0]; a += wp[1]*iv[1]; a += wp[2]*iv[2];
            a += wp[3]*iv[3]; a += wp[4]*iv[4]; a += wp[5]*iv[5];
            a += wp[6]*iv[6]; a += wp[7]*iv[7]; a += wp[8]*iv[8];
            acc[co] = a;
        }
    }
#pragma unroll
    for (int co = 0; co < 16; ++co)
        out[(size_t)(co0+co)*16384 + (size_t)(z0+zh)*128 + x] = acc[co];
}

// ---------------- instance-norm stats ----------------
__global__ __launch_bounds__(256) void k_instnorm_stats(const float* __restrict__ out,
                                                        float* __restrict__ stats) {
    __shared__ float r1[256], r2[256];
    int co = blockIdx.x, tid = threadIdx.x;
    const float* p = out + (size_t)co*16384;
    float s1 = 0.0f, s2 = 0.0f;
    for (int i = tid; i < 16384; i += 256) { float v = p[i]; s1 += v; s2 += v*v; }
    r1[tid] = s1; r2[tid] = s2;
    __syncthreads();
    for (int off = 128; off > 0; off >>= 1) {
        if (tid < off) { r1[tid] += r1[tid+off]; r2[tid] += r2[tid+off]; }
        __syncthreads();
    }
    if (tid == 0) {
        float mean = r1[0] * (1.0f/16384.0f);
        float var  = r2[0] * (1.0f/16384.0f) - mean*mean;
        stats[co*2]   = mean;
        stats[co*2+1] = rsqrtf(var + 1e-5f);
    }
}

// ---------------- normalize + exact GELU (in place) ----------------
__global__ __launch_bounds__(256) void k_gelu(float* __restrict__ out,
                                              const float* __restrict__ stats) {
    int i = blockIdx.x*256 + threadIdx.x;
    int co = i >> 14;
    float v = out[i];
    float r = (v - stats[co*2]) * stats[co*2+1];
    out[i] = 0.5f * r * (1.0f + erff(r * 0.70710678118654752f));
}

extern "C" void kernel_launch(void* const* d_in, const int* in_sizes, int n_in,
                              void* d_out, int out_size, void* d_ws, size_t ws_size,
                              hipStream_t stream) {
    const float* cam_feat = (const float*)d_in[0];
    const float* intrins  = (const float*)d_in[1];
    const float* rots     = (const float*)d_in[2];
    const float* trans    = (const float*)d_in[3];
    const float* conv_w   = (const float*)d_in[4];
    float* out = (float*)d_out;
    float* ws  = (float*)d_ws;

    float* mats  = ws;                                   // 160
    float* uv    = ws + 160;                             // NVOX*12 = 1,572,864
    float* featT = uv + (size_t)NVOX*12;                 // 4,300,800
    float* bevin = featT + (size_t)SNUM*HW*CNUM;         // 16,777,216
    float* stats = bevin + (size_t)1024*16384;           // 256
    // total ~90.6 MB

    hipLaunchKernelGGL(k_setup, dim3(1), dim3(64), 0, stream, intrins, rots, trans, mats);
    hipLaunchKernelGGL(k_tfeat, dim3(HW/32, CNUM/32, SNUM), dim3(32,8), 0, stream, cam_feat, featT);
    hipLaunchKernelGGL(k_geo, dim3(NVOX/256), dim3(256), 0, stream, mats, uv);
    hipLaunchKernelGGL(k_sample, dim3(NVOX/16), dim3(256), 0, stream, featT, uv, bevin);
    hipLaunchKernelGGL(k_conv, dim3(8, 64), dim3(256), 0, stream, bevin, conv_w, out);
    hipLaunchKernelGGL(k_instnorm_stats, dim3(128), dim3(256), 0, stream, out, stats);
    hipLaunchKernelGGL(k_gelu, dim3(8192), dim3(256), 0, stream, out, stats);
}

// Round 2
// 245.214 us; speedup vs baseline: 5.9843x; 5.9843x over previous
//
#include <hip/hip_runtime.h>
#include <cmath>

// ---------------- problem constants ----------------
#define SNUM 6
#define CNUM 128
#define HF 56
#define WF 100
#define HW (HF*WF)          // 5600
#define ZN 128
#define YN 8
#define XN 128
#define NVOX (ZN*YN*XN)     // 131072

typedef __attribute__((ext_vector_type(8))) short bf16x8;
typedef __attribute__((ext_vector_type(4))) float f32x4;
typedef __attribute__((ext_vector_type(4))) int   i32x4;

__device__ __forceinline__ unsigned short f2bf(float f) {
    unsigned u = __builtin_bit_cast(unsigned, f);
    unsigned r = (u + 0x7FFFu + ((u >> 16) & 1u)) >> 16;   // RNE
    return (unsigned short)r;
}

// ---------------- setup: per-camera matrices ----------------
__global__ void k_setup(const float* __restrict__ intrins,
                        const float* __restrict__ rots,
                        const float* __restrict__ trans,
                        float* __restrict__ mats) {
    int s = threadIdx.x;
    if (s >= SNUM) return;
    float R0[9], Rs[9], t0[3], ts[3];
    for (int i = 0; i < 9; ++i) { R0[i] = rots[i]; Rs[i] = rots[s*9 + i]; }
    for (int i = 0; i < 3; ++i) { t0[i] = trans[i]; ts[i] = trans[s*3 + i]; }
    float M[3][4];
    float d0 = t0[0]-ts[0], d1 = t0[1]-ts[1], d2 = t0[2]-ts[2];
    for (int i = 0; i < 3; ++i) {
        for (int j = 0; j < 3; ++j)
            M[i][j] = Rs[0*3+i]*R0[0*3+j] + Rs[1*3+i]*R0[1*3+j] + Rs[2*3+i]*R0[2*3+j];
        M[i][3] = Rs[0*3+i]*d0 + Rs[1*3+i]*d1 + Rs[2*3+i]*d2;
    }
    const float sx = (float)WF/800.0f, sy = (float)HF/448.0f;
    float fx = intrins[s*16 + 0]*sx, fy = intrins[s*16 + 5]*sy;
    float cx = intrins[s*16 + 2]*sx, cy = intrins[s*16 + 6]*sy;
    float* o = mats + s*24;
    for (int j = 0; j < 4; ++j) {
        o[0*4+j]      = M[0][j];
        o[1*4+j]      = M[1][j];
        o[2*4+j]      = M[2][j];
        o[12 + 0*4+j] = fx*M[0][j] + cx*M[2][j];
        o[12 + 1*4+j] = fy*M[1][j] + cy*M[2][j];
        o[12 + 2*4+j] = M[2][j];
    }
}

// ---------------- transpose cam_feat (S,C,HW) -> featT (S,HW,C) ----------------
__global__ __launch_bounds__(256) void k_tfeat(const float* __restrict__ cf,
                                               float* __restrict__ featT) {
    __shared__ float t[32][33];
    int s = blockIdx.z;
    int p0 = blockIdx.x * 32, c0 = blockIdx.y * 32;
    int tx = threadIdx.x, ty = threadIdx.y;   // 32 x 8
#pragma unroll
    for (int k = 0; k < 4; ++k) {
        int r = ty + k*8;
        t[r][tx] = cf[((size_t)s*CNUM + c0 + r)*HW + p0 + tx];
    }
    __syncthreads();
#pragma unroll
    for (int k = 0; k < 4; ++k) {
        int r = ty + k*8;
        featT[((size_t)s*HW + p0 + r)*CNUM + c0 + tx] = t[tx][r];
    }
}

// ---------------- per-voxel projection -> (ux,uy) per camera ----------------
__global__ __launch_bounds__(256) void k_geo(const float* __restrict__ mats,
                                             float* __restrict__ uv) {
#pragma clang fp contract(off)
    int n = blockIdx.x * 256 + threadIdx.x;
    int zi = n >> 10, yi = (n >> 7) & 7, xi = n & 127;
    float xr = -49.609375f + (float)xi * 0.78125f;
    float yr = (-4.9f + 0.625f) + (float)yi * 1.25f;
    float zr = -49.609375f + (float)zi * 0.78125f;
#pragma unroll
    for (int s = 0; s < SNUM; ++s) {
        const float* m = mats + s*24;
        float zc = m[8]*xr  + m[9]*yr  + m[10]*zr + m[11];
        float ph = m[12]*xr + m[13]*yr + m[14]*zr + m[15];
        float qh = m[16]*xr + m[17]*yr + m[18]*zr + m[19];
        float denom = fmaxf(zc, 1e-6f);
        float px = ph / denom, py = qh / denom;
        bool valid = (px > -0.5f) & (px < (float)WF - 0.5f) &
                     (py > -0.5f) & (py < (float)HF - 0.5f) & (zc > 0.0f);
        float ux = -10000.0f, uy = -10000.0f;
        if (valid) {
            float gx = 2.0f*px/((float)WF - 1.0f) - 1.0f;
            float gy = 2.0f*py/((float)HF - 1.0f) - 1.0f;
            gx = fminf(fmaxf(gx, -2.0f), 2.0f);
            gy = fminf(fmaxf(gy, -2.0f), 2.0f);
            ux = ((gx + 1.0f)*(float)WF - 1.0f)*0.5f;
            uy = ((gy + 1.0f)*(float)HF - 1.0f)*0.5f;
        }
        uv[(n*SNUM + s)*2]     = ux;
        uv[(n*SNUM + s)*2 + 1] = uy;
    }
}

// ---------------- bilinear sample + masked camera mean -> bevin bf16 [z][x][ci] ----
// block = 256 thr covers one z, 2 x, all 8 y, all 128 c. ci = c*8+y contiguous write.
__global__ __launch_bounds__(256) void k_sample(const float* __restrict__ featT,
                                                const float* __restrict__ uv,
                                                unsigned short* __restrict__ bevin) {
#pragma clang fp contract(off)
    __shared__ float xch[16][132];        // [vs = y*2+xs][c]
    const int tid = threadIdx.x;
    const int b = blockIdx.x;             // 8192 = 128 z * 64 x-pairs
    const int z = b >> 6, x0 = (b & 63) * 2;
    const int cl = tid & 15, vs = tid >> 4;
    const int y = vs >> 1, xs = vs & 1;
    const int n = z*1024 + y*128 + x0 + xs;
    float sum[8], cnt[8];
#pragma unroll
    for (int k = 0; k < 8; ++k) { sum[k] = 0.0f; cnt[k] = 0.0f; }
    for (int s = 0; s < SNUM; ++s) {
        float2 u = ((const float2*)uv)[n*SNUM + s];
        if (u.x < -999.0f) continue;
        float x0f = floorf(u.x), y0f = floorf(u.y);
        float wx = u.x - x0f, wy = u.y - y0f;
        int ix = (int)x0f, iy = (int)y0f;
        float w00 = (1.0f-wx)*(1.0f-wy), w10 = wx*(1.0f-wy);
        float w01 = (1.0f-wx)*wy,        w11 = wx*wy;
        bool bx0 = (ix >= 0) & (ix < WF);
        bool bx1 = (ix >= -1) & (ix < WF-1);
        bool by0 = (iy >= 0) & (iy < HF);
        bool by1 = (iy >= -1) & (iy < HF-1);
        bool c00 = bx0 & by0, c10 = bx1 & by0, c01 = bx0 & by1, c11 = bx1 & by1;
        const float* fb = featT + (size_t)s * (HW*CNUM) + cl;
        long r0 = (long)(iy*WF + ix) * CNUM;
#pragma unroll
        for (int k = 0; k < 8; ++k) {
            int co = k*16;
            float v = 0.0f;
            if (c00) v = v + w00 * fb[r0 + co];
            if (c10) v = v + w10 * fb[r0 + co + CNUM];
            if (c01) v = v + w01 * fb[r0 + co + WF*CNUM];
            if (c11) v = v + w11 * fb[r0 + co + WF*CNUM + CNUM];
            sum[k] += v;
            cnt[k] += (v != 0.0f) ? 1.0f : 0.0f;
        }
    }
#pragma unroll
    for (int k = 0; k < 8; ++k)
        xch[vs][k*16 + cl] = sum[k] / (1e-6f + cnt[k]);
    __syncthreads();
    // pack to bf16: element e = c*8+y at bevin[(z*128 + x0+xs)*1024 + e]
#pragma unroll
    for (int j = 0; j < 4; ++j) {
        int m = tid + j*256;              // uint index in [0,1024)
        int xs2 = m >> 9;
        int r = m & 511;                  // elements 2r, 2r+1
        int c = (2*r) >> 3, y0 = (2*r) & 7;
        float v0 = xch[y0*2 + xs2][c];
        float v1 = xch[(y0+1)*2 + xs2][c];
        unsigned pk = (unsigned)f2bf(v0) | ((unsigned)f2bf(v1) << 16);
        ((unsigned*)bevin)[(size_t)(z*128 + x0 + xs2)*512 + r] = pk;
    }
}

// ---------------- weight prep: conv_w [co][ci][3][3] f32 -> w2 [tap][co][ci] bf16 ----
__global__ __launch_bounds__(256) void k_wprep(const float* __restrict__ w,
                                               unsigned short* __restrict__ w2) {
    int i = blockIdx.x*256 + threadIdx.x;     // over 9*128*1024
    if (i >= 9*128*1024) return;
    int ci = i & 1023; int rest = i >> 10; int co = rest & 127; int tap = rest >> 7;
    w2[i] = f2bf(w[((size_t)co*1024 + ci)*9 + tap]);
}

// ---------------- MFMA implicit-GEMM conv 3x3 ----------------
// grid (128 z, 2 co-half), block 256 = 4 waves (2 co x 2 x), wave tile 32co x 64x
__global__ __launch_bounds__(256) void k_conv_mfma(
        const unsigned short* __restrict__ bevin,   // [z][x][1024] bf16
        const unsigned short* __restrict__ w2,      // [tap][co][1024] bf16
        float* __restrict__ out) {
    __shared__ unsigned short lds[2][12*130*8];     // [buf][(zr*4+kg)*130 + xpad][8ci]
    const int tid  = threadIdx.x;
    const int z0   = blockIdx.x;
    const int coh  = blockIdx.y;
    const int lane = tid & 63, wid = tid >> 6;
    const int wr = wid >> 1, wx = wid & 1;
    const int co_base = coh*64 + wr*32;
    const int l15 = lane & 15, lhi = lane >> 4;

    // zero x-padding columns (xpad=0 and xpad=129) once; never overwritten
    if (tid < 48) {
        int bf = tid & 1, q = tid >> 1;      // q in [0,24)
        int row = q >> 1, side = q & 1;      // row in [0,12)
        *(i32x4*)&lds[bf][(row*130 + side*129)*8] = i32x4{0,0,0,0};
    }

    f32x4 acc[2][4];
#pragma unroll
    for (int f = 0; f < 2; ++f)
#pragma unroll
        for (int nf = 0; nf < 4; ++nf) acc[f][nf] = f32x4{0.f,0.f,0.f,0.f};

    // staging decomposition: i = tid + j*256; kg=i&3, x=(i>>2)&127, zr=i>>9
    const int s_kg = tid & 3, s_x = (tid >> 2) & 63;  // j adds to upper bits

    i32x4 pre[6];
    bool  pv[6];
#define STAGE_LOAD(CI0)                                                        \
    {                                                                          \
        _Pragma("unroll")                                                      \
        for (int j = 0; j < 6; ++j) {                                          \
            int i  = tid + j*256;                                              \
            int kg = i & 3, x = (i >> 2) & 127, zr = i >> 9;                   \
            int zz = z0 - 1 + zr;                                              \
            pv[j] = ((unsigned)zz < 128u);                                     \
            if (pv[j])                                                         \
                pre[j] = *(const i32x4*)&bevin[((size_t)(zz*128 + x))*1024 + (CI0) + kg*8]; \
        }                                                                      \
    }
#define STAGE_WRITE(BUF)                                                       \
    {                                                                          \
        _Pragma("unroll")                                                      \
        for (int j = 0; j < 6; ++j) {                                          \
            int i  = tid + j*256;                                              \
            int kg = i & 3, x = (i >> 2) & 127, zr = i >> 9;                   \
            if (pv[j])                                                         \
                *(i32x4*)&lds[BUF][(((zr*4 + kg)*130) + 1 + x)*8] = pre[j];    \
        }                                                                      \
    }

    STAGE_LOAD(0);
    __syncthreads();   // cover the padding zero-fill too
    STAGE_WRITE(0);
    __syncthreads();

    for (int c = 0; c < 32; ++c) {
        const int ci0 = c*32;
        if (c + 1 < 32) STAGE_LOAD(ci0 + 32);

        const unsigned short* lb = lds[c & 1];
#pragma unroll
        for (int dz = 0; dz < 3; ++dz) {
            if ((unsigned)(z0 - 1 + dz) >= 128u) continue;
#pragma unroll
            for (int dx = 0; dx < 3; ++dx) {
                const int tap = dz*3 + dx;
                bf16x8 a0 = *(const bf16x8*)&w2[((size_t)(tap*128 + co_base      + l15))*1024 + ci0 + lhi*8];
                bf16x8 a1 = *(const bf16x8*)&w2[((size_t)(tap*128 + co_base + 16 + l15))*1024 + ci0 + lhi*8];
#pragma unroll
                for (int nf = 0; nf < 4; ++nf) {
                    int xp = wx*64 + nf*16 + l15 + dx;   // padded x index
                    bf16x8 b = *(const bf16x8*)&lb[(((dz*4 + lhi)*130) + xp)*8];
                    acc[0][nf] = __builtin_amdgcn_mfma_f32_16x16x32_bf16(a0, b, acc[0][nf], 0, 0, 0);
                    acc[1][nf] = __builtin_amdgcn_mfma_f32_16x16x32_bf16(a1, b, acc[1][nf], 0, 0, 0);
                }
            }
        }
        __syncthreads();
        if (c + 1 < 32) STAGE_WRITE((c + 1) & 1);
        __syncthreads();
    }

    // epilogue: D row=(lhi*4+r), col=l15
#pragma unroll
    for (int f = 0; f < 2; ++f)
#pragma unroll
        for (int nf = 0; nf < 4; ++nf)
#pragma unroll
            for (int r = 0; r < 4; ++r) {
                int co = co_base + f*16 + lhi*4 + r;
                out[(size_t)co*16384 + z0*128 + wx*64 + nf*16 + l15] = acc[f][nf][r];
            }
#undef STAGE_LOAD
#undef STAGE_WRITE
}

// ---------------- instance-norm stats ----------------
__global__ __launch_bounds__(256) void k_instnorm_stats(const float* __restrict__ out,
                                                        float* __restrict__ stats) {
    __shared__ float r1[256], r2[256];
    int co = blockIdx.x, tid = threadIdx.x;
    const float* p = out + (size_t)co*16384;
    float s1 = 0.0f, s2 = 0.0f;
    for (int i = tid; i < 16384; i += 256) { float v = p[i]; s1 += v; s2 += v*v; }
    r1[tid] = s1; r2[tid] = s2;
    __syncthreads();
    for (int off = 128; off > 0; off >>= 1) {
        if (tid < off) { r1[tid] += r1[tid+off]; r2[tid] += r2[tid+off]; }
        __syncthreads();
    }
    if (tid == 0) {
        float mean = r1[0] * (1.0f/16384.0f);
        float var  = r2[0] * (1.0f/16384.0f) - mean*mean;
        stats[co*2]   = mean;
        stats[co*2+1] = rsqrtf(var + 1e-5f);
    }
}

// ---------------- normalize + exact GELU (in place) ----------------
__global__ __launch_bounds__(256) void k_gelu(float* __restrict__ out,
                                              const float* __restrict__ stats) {
    int i = blockIdx.x*256 + threadIdx.x;
    int co = i >> 14;
    float v = out[i];
    float r = (v - stats[co*2]) * stats[co*2+1];
    out[i] = 0.5f * r * (1.0f + erff(r * 0.70710678118654752f));
}

extern "C" void kernel_launch(void* const* d_in, const int* in_sizes, int n_in,
                              void* d_out, int out_size, void* d_ws, size_t ws_size,
                              hipStream_t stream) {
    const float* cam_feat = (const float*)d_in[0];
    const float* intrins  = (const float*)d_in[1];
    const float* rots     = (const float*)d_in[2];
    const float* trans    = (const float*)d_in[3];
    const float* conv_w   = (const float*)d_in[4];
    float* out = (float*)d_out;
    float* ws  = (float*)d_ws;

    float* mats  = ws;                                      // 160 f
    float* uv    = ws + 160;                                // NVOX*12 f
    float* featT = uv + (size_t)NVOX*12;                    // 4,300,800 f
    unsigned short* bevin = (unsigned short*)(featT + (size_t)SNUM*HW*CNUM);  // 16,777,216 bf16
    unsigned short* w2    = bevin + (size_t)16384*1024;     // 1,179,648 bf16
    float* stats = (float*)(w2 + 9*128*1024);               // 256 f
    // total ~59.5 MB

    hipLaunchKernelGGL(k_setup, dim3(1), dim3(64), 0, stream, intrins, rots, trans, mats);
    hipLaunchKernelGGL(k_tfeat, dim3(HW/32, CNUM/32, SNUM), dim3(32,8), 0, stream, cam_feat, featT);
    hipLaunchKernelGGL(k_geo, dim3(NVOX/256), dim3(256), 0, stream, mats, uv);
    hipLaunchKernelGGL(k_wprep, dim3((9*128*1024 + 255)/256), dim3(256), 0, stream, conv_w, w2);
    hipLaunchKernelGGL(k_sample, dim3(8192), dim3(256), 0, stream, featT, uv, bevin);
    hipLaunchKernelGGL(k_conv_mfma, dim3(128, 2), dim3(256), 0, stream, bevin, w2, out);
    hipLaunchKernelGGL(k_instnorm_stats, dim3(128), dim3(256), 0, stream, out, stats);
    hipLaunchKernelGGL(k_gelu, dim3(8192), dim3(256), 0, stream, out, stats);
}

// Round 3
// 157.071 us; speedup vs baseline: 9.3426x; 1.5612x over previous
//
#include <hip/hip_runtime.h>
#include <cmath>

// ---------------- problem constants ----------------
#define SNUM 6
#define CNUM 128
#define HF 56
#define WF 100
#define HW (HF*WF)          // 5600
#define ZN 128
#define YN 8
#define XN 128
#define NVOX (ZN*YN*XN)     // 131072

typedef __attribute__((ext_vector_type(8))) short bf16x8;
typedef __attribute__((ext_vector_type(4))) float f32x4;
typedef __attribute__((ext_vector_type(4))) int   i32x4;

__device__ __forceinline__ unsigned short f2bf(float f) {
    unsigned u = __builtin_bit_cast(unsigned, f);
    unsigned r = (u + 0x7FFFu + ((u >> 16) & 1u)) >> 16;   // RNE
    return (unsigned short)r;
}
__device__ __forceinline__ float bf2f(unsigned short h) {
    unsigned u = (unsigned)h << 16;
    return __builtin_bit_cast(float, u);
}

// ---------------- setup: per-camera matrices ----------------
__global__ void k_setup(const float* __restrict__ intrins,
                        const float* __restrict__ rots,
                        const float* __restrict__ trans,
                        float* __restrict__ mats) {
    int s = threadIdx.x;
    if (s >= SNUM) return;
    float R0[9], Rs[9], t0[3], ts[3];
    for (int i = 0; i < 9; ++i) { R0[i] = rots[i]; Rs[i] = rots[s*9 + i]; }
    for (int i = 0; i < 3; ++i) { t0[i] = trans[i]; ts[i] = trans[s*3 + i]; }
    float M[3][4];
    float d0 = t0[0]-ts[0], d1 = t0[1]-ts[1], d2 = t0[2]-ts[2];
    for (int i = 0; i < 3; ++i) {
        for (int j = 0; j < 3; ++j)
            M[i][j] = Rs[0*3+i]*R0[0*3+j] + Rs[1*3+i]*R0[1*3+j] + Rs[2*3+i]*R0[2*3+j];
        M[i][3] = Rs[0*3+i]*d0 + Rs[1*3+i]*d1 + Rs[2*3+i]*d2;
    }
    const float sx = (float)WF/800.0f, sy = (float)HF/448.0f;
    float fx = intrins[s*16 + 0]*sx, fy = intrins[s*16 + 5]*sy;
    float cx = intrins[s*16 + 2]*sx, cy = intrins[s*16 + 6]*sy;
    float* o = mats + s*24;
    for (int j = 0; j < 4; ++j) {
        o[0*4+j]      = M[0][j];
        o[1*4+j]      = M[1][j];
        o[2*4+j]      = M[2][j];
        o[12 + 0*4+j] = fx*M[0][j] + cx*M[2][j];
        o[12 + 1*4+j] = fy*M[1][j] + cy*M[2][j];
        o[12 + 2*4+j] = M[2][j];
    }
}

// ---------------- transpose cam_feat (S,C,HW) f32 -> featT (S,HW,C) bf16 -------
__global__ __launch_bounds__(256) void k_tfeat(const float* __restrict__ cf,
                                               unsigned short* __restrict__ featT) {
    __shared__ float t[32][33];
    int s = blockIdx.z;
    int p0 = blockIdx.x * 32, c0 = blockIdx.y * 32;
    int tx = threadIdx.x, ty = threadIdx.y;   // 32 x 8
#pragma unroll
    for (int k = 0; k < 4; ++k) {
        int r = ty + k*8;
        t[r][tx] = cf[((size_t)s*CNUM + c0 + r)*HW + p0 + tx];
    }
    __syncthreads();
#pragma unroll
    for (int k = 0; k < 4; ++k) {
        int r = ty + k*8;
        featT[((size_t)s*HW + p0 + r)*CNUM + c0 + tx] = f2bf(t[tx][r]);
    }
}

// ---------------- per-voxel projection -> (ux,uy) per camera ----------------
__global__ __launch_bounds__(256) void k_geo(const float* __restrict__ mats,
                                             float* __restrict__ uv) {
#pragma clang fp contract(off)
    int n = blockIdx.x * 256 + threadIdx.x;
    int zi = n >> 10, yi = (n >> 7) & 7, xi = n & 127;
    float xr = -49.609375f + (float)xi * 0.78125f;
    float yr = (-4.9f + 0.625f) + (float)yi * 1.25f;
    float zr = -49.609375f + (float)zi * 0.78125f;
#pragma unroll
    for (int s = 0; s < SNUM; ++s) {
        const float* m = mats + s*24;
        float zc = m[8]*xr  + m[9]*yr  + m[10]*zr + m[11];
        float ph = m[12]*xr + m[13]*yr + m[14]*zr + m[15];
        float qh = m[16]*xr + m[17]*yr + m[18]*zr + m[19];
        float denom = fmaxf(zc, 1e-6f);
        float px = ph / denom, py = qh / denom;
        bool valid = (px > -0.5f) & (px < (float)WF - 0.5f) &
                     (py > -0.5f) & (py < (float)HF - 0.5f) & (zc > 0.0f);
        float ux = -10000.0f, uy = -10000.0f;
        if (valid) {
            float gx = 2.0f*px/((float)WF - 1.0f) - 1.0f;
            float gy = 2.0f*py/((float)HF - 1.0f) - 1.0f;
            gx = fminf(fmaxf(gx, -2.0f), 2.0f);
            gy = fminf(fmaxf(gy, -2.0f), 2.0f);
            ux = ((gx + 1.0f)*(float)WF - 1.0f)*0.5f;
            uy = ((gy + 1.0f)*(float)HF - 1.0f)*0.5f;
        }
        uv[(n*SNUM + s)*2]     = ux;
        uv[(n*SNUM + s)*2 + 1] = uy;
    }
}

// ---------------- bilinear sample + masked camera mean -> bevin bf16 [z][x][ci] ----
// block = 256 thr: one z, 2 x, 8 y, 128 c. Thread owns 8 contiguous channels ->
// one bf16x8 (16B) load per corner per camera.
__global__ __launch_bounds__(256) void k_sample(const unsigned short* __restrict__ featT,
                                                const float* __restrict__ uv,
                                                unsigned short* __restrict__ bevin) {
#pragma clang fp contract(off)
    __shared__ float xch[16][132];        // [vs = y*2+xs][c]
    const int tid = threadIdx.x;
    const int b = blockIdx.x;             // 8192 = 128 z * 64 x-pairs
    const int z = b >> 6, x0 = (b & 63) * 2;
    const int cl = tid & 15, vs = tid >> 4;
    const int y = vs >> 1, xs = vs & 1;
    const int n = z*1024 + y*128 + x0 + xs;
    const bf16x8 zz8 = {0,0,0,0,0,0,0,0};
    float sum[8], cnt[8];
#pragma unroll
    for (int k = 0; k < 8; ++k) { sum[k] = 0.0f; cnt[k] = 0.0f; }
    for (int s = 0; s < SNUM; ++s) {
        float2 u = ((const float2*)uv)[n*SNUM + s];
        if (u.x < -999.0f) continue;
        float x0f = floorf(u.x), y0f = floorf(u.y);
        float wx = u.x - x0f, wy = u.y - y0f;
        int ix = (int)x0f, iy = (int)y0f;
        float w00 = (1.0f-wx)*(1.0f-wy), w10 = wx*(1.0f-wy);
        float w01 = (1.0f-wx)*wy,        w11 = wx*wy;
        bool bx0 = (ix >= 0) & (ix < WF);
        bool bx1 = (ix >= -1) & (ix < WF-1);
        bool by0 = (iy >= 0) & (iy < HF);
        bool by1 = (iy >= -1) & (iy < HF-1);
        bool c00 = bx0 & by0, c10 = bx1 & by0, c01 = bx0 & by1, c11 = bx1 & by1;
        const unsigned short* fb = featT + (size_t)s * (HW*CNUM) + cl*8;
        long r0 = (long)(iy*WF + ix) * CNUM;
        bf16x8 v00 = c00 ? *(const bf16x8*)(fb + r0)                 : zz8;
        bf16x8 v10 = c10 ? *(const bf16x8*)(fb + r0 + CNUM)          : zz8;
        bf16x8 v01 = c01 ? *(const bf16x8*)(fb + r0 + WF*CNUM)       : zz8;
        bf16x8 v11 = c11 ? *(const bf16x8*)(fb + r0 + WF*CNUM + CNUM): zz8;
#pragma unroll
        for (int k = 0; k < 8; ++k) {
            float v = 0.0f;
            v = v + w00 * bf2f((unsigned short)v00[k]);
            v = v + w10 * bf2f((unsigned short)v10[k]);
            v = v + w01 * bf2f((unsigned short)v01[k]);
            v = v + w11 * bf2f((unsigned short)v11[k]);
            sum[k] += v;
            cnt[k] += (v != 0.0f) ? 1.0f : 0.0f;
        }
    }
#pragma unroll
    for (int k = 0; k < 8; ++k)
        xch[vs][cl*8 + k] = sum[k] / (1e-6f + cnt[k]);
    __syncthreads();
    // pack to bf16: element e = c*8+y at bevin[(z*128 + x0+xs)*1024 + e]
#pragma unroll
    for (int j = 0; j < 4; ++j) {
        int m = tid + j*256;              // uint index in [0,1024)
        int xs2 = m >> 9;
        int r = m & 511;                  // elements 2r, 2r+1
        int c = (2*r) >> 3, y0 = (2*r) & 7;
        float v0 = xch[y0*2 + xs2][c];
        float v1 = xch[(y0+1)*2 + xs2][c];
        unsigned pk = (unsigned)f2bf(v0) | ((unsigned)f2bf(v1) << 16);
        ((unsigned*)bevin)[(size_t)(z*128 + x0 + xs2)*512 + r] = pk;
    }
}

// ---------------- weight prep: conv_w [co][ci][3][3] f32 -> w2 [tap][co][ci] bf16 ----
__global__ __launch_bounds__(256) void k_wprep(const float* __restrict__ w,
                                               unsigned short* __restrict__ w2) {
    int i = blockIdx.x*256 + threadIdx.x;     // over 9*128*1024
    if (i >= 9*128*1024) return;
    int ci = i & 1023; int rest = i >> 10; int co = rest & 127; int tap = rest >> 7;
    w2[i] = f2bf(w[((size_t)co*1024 + ci)*9 + tap]);
}

// ---------------- MFMA implicit-GEMM conv 3x3 ----------------
// grid (128 z, 2 co-half), block 256 = 4 waves (2 co x 2 x), wave tile 32co x 64x
// A (weights) register-double-buffered per ci-chunk; B (activations) LDS dbuf;
// single barrier per chunk.
__global__ __launch_bounds__(256, 1) void k_conv_mfma(
        const unsigned short* __restrict__ bevin,   // [z][x][1024] bf16
        const unsigned short* __restrict__ w2,      // [tap][co][1024] bf16
        float* __restrict__ out) {
    __shared__ unsigned short lds[2][12*130*8];     // [buf][(zr*4+kg)*130 + xpad][8ci]
    const int tid  = threadIdx.x;
    const int z0   = blockIdx.x;
    const int coh  = blockIdx.y;
    const int lane = tid & 63, wid = tid >> 6;
    const int wr = wid >> 1, wx = wid & 1;
    const int co_base = coh*64 + wr*32;
    const int l15 = lane & 15, lhi = lane >> 4;

    // zero x-padding columns (xpad=0 and xpad=129) once; never overwritten
    if (tid < 48) {
        int bf = tid & 1, q = tid >> 1;      // q in [0,24)
        int row = q >> 1, side = q & 1;      // row in [0,12)
        *(i32x4*)&lds[bf][(row*130 + side*129)*8] = i32x4{0,0,0,0};
    }

    f32x4 acc[2][4];
#pragma unroll
    for (int f = 0; f < 2; ++f)
#pragma unroll
        for (int nf = 0; nf < 4; ++nf) acc[f][nf] = f32x4{0.f,0.f,0.f,0.f};

    const unsigned short* aw0 = w2 + ((size_t)(co_base      + l15))*1024 + lhi*8;
    const unsigned short* aw1 = w2 + ((size_t)(co_base + 16 + l15))*1024 + lhi*8;

    bf16x8 afr0[18], afr1[18];
    i32x4 pre[6];
    bool  pv[6];

#define A_LOAD(DST, CI0)                                                       \
    {                                                                          \
        _Pragma("unroll")                                                      \
        for (int t = 0; t < 9; ++t) {                                          \
            DST[t*2]   = *(const bf16x8*)(aw0 + (size_t)t*131072 + (CI0));     \
            DST[t*2+1] = *(const bf16x8*)(aw1 + (size_t)t*131072 + (CI0));     \
        }                                                                      \
    }
#define B_LOAD(CI0)                                                            \
    {                                                                          \
        _Pragma("unroll")                                                      \
        for (int j = 0; j < 6; ++j) {                                          \
            int i  = tid + j*256;                                              \
            int kg = i & 3, x = (i >> 2) & 127, zr = i >> 9;                   \
            int zz = z0 - 1 + zr;                                              \
            pv[j] = ((unsigned)zz < 128u);                                     \
            if (pv[j])                                                         \
                pre[j] = *(const i32x4*)&bevin[((size_t)(zz*128 + x))*1024 + (CI0) + kg*8]; \
        }                                                                      \
    }
#define B_WRITE(BUF)                                                           \
    {                                                                          \
        _Pragma("unroll")                                                      \
        for (int j = 0; j < 6; ++j) {                                          \
            int i  = tid + j*256;                                              \
            int kg = i & 3, x = (i >> 2) & 127, zr = i >> 9;                   \
            if (pv[j])                                                         \
                *(i32x4*)&lds[BUF][(((zr*4 + kg)*130) + 1 + x)*8] = pre[j];    \
        }                                                                      \
    }
#define COMPUTE(BUF, AFR)                                                      \
    {                                                                          \
        _Pragma("unroll")                                                      \
        for (int dz = 0; dz < 3; ++dz) {                                       \
            if ((unsigned)(z0 - 1 + dz) < 128u) {                              \
                _Pragma("unroll")                                              \
                for (int dx = 0; dx < 3; ++dx) {                               \
                    bf16x8 a0 = AFR[(dz*3+dx)*2];                              \
                    bf16x8 a1 = AFR[(dz*3+dx)*2+1];                            \
                    _Pragma("unroll")                                          \
                    for (int nf = 0; nf < 4; ++nf) {                           \
                        int xp = wx*64 + nf*16 + l15 + dx;                     \
                        bf16x8 bfr = *(const bf16x8*)&lds[BUF][(((dz*4 + lhi)*130) + xp)*8]; \
                        acc[0][nf] = __builtin_amdgcn_mfma_f32_16x16x32_bf16(a0, bfr, acc[0][nf], 0, 0, 0); \
                        acc[1][nf] = __builtin_amdgcn_mfma_f32_16x16x32_bf16(a1, bfr, acc[1][nf], 0, 0, 0); \
                    }                                                          \
                }                                                              \
            }                                                                  \
        }                                                                      \
    }

    // prologue: chunk 0 -> buf0 / afr0
    B_LOAD(0);
    A_LOAD(afr0, 0);
    __syncthreads();     // pad zero-fill visible
    B_WRITE(0);
    __syncthreads();

    for (int cc = 0; cc < 16; ++cc) {
        const int ci0 = cc*64;
        // --- chunk cc*2 : compute buf0/afr0, prefetch chunk cc*2+1 -> buf1/afr1
        B_LOAD(ci0 + 32);
        A_LOAD(afr1, ci0 + 32);
        COMPUTE(0, afr0);
        B_WRITE(1);
        __syncthreads();
        // --- chunk cc*2+1 : compute buf1/afr1, prefetch chunk cc*2+2 -> buf0/afr0
        if (cc < 15) {
            B_LOAD(ci0 + 64);
            A_LOAD(afr0, ci0 + 64);
        }
        COMPUTE(1, afr1);
        if (cc < 15) {
            B_WRITE(0);
            __syncthreads();
        }
    }

    // epilogue: D row=(lhi*4+r) -> co, col=l15 -> x
#pragma unroll
    for (int f = 0; f < 2; ++f)
#pragma unroll
        for (int nf = 0; nf < 4; ++nf)
#pragma unroll
            for (int r = 0; r < 4; ++r) {
                int co = co_base + f*16 + lhi*4 + r;
                out[(size_t)co*16384 + z0*128 + wx*64 + nf*16 + l15] = acc[f][nf][r];
            }
#undef A_LOAD
#undef B_LOAD
#undef B_WRITE
#undef COMPUTE
}

// ---------------- instance-norm stats ----------------
__global__ __launch_bounds__(256) void k_instnorm_stats(const float* __restrict__ out,
                                                        float* __restrict__ stats) {
    __shared__ float r1[256], r2[256];
    int co = blockIdx.x, tid = threadIdx.x;
    const float* p = out + (size_t)co*16384;
    float s1 = 0.0f, s2 = 0.0f;
    for (int i = tid; i < 16384; i += 256) { float v = p[i]; s1 += v; s2 += v*v; }
    r1[tid] = s1; r2[tid] = s2;
    __syncthreads();
    for (int off = 128; off > 0; off >>= 1) {
        if (tid < off) { r1[tid] += r1[tid+off]; r2[tid] += r2[tid+off]; }
        __syncthreads();
    }
    if (tid == 0) {
        float mean = r1[0] * (1.0f/16384.0f);
        float var  = r2[0] * (1.0f/16384.0f) - mean*mean;
        stats[co*2]   = mean;
        stats[co*2+1] = rsqrtf(var + 1e-5f);
    }
}

// ---------------- normalize + exact GELU (in place) ----------------
__global__ __launch_bounds__(256) void k_gelu(float* __restrict__ out,
                                              const float* __restrict__ stats) {
    int i = blockIdx.x*256 + threadIdx.x;
    int co = i >> 14;
    float v = out[i];
    float r = (v - stats[co*2]) * stats[co*2+1];
    out[i] = 0.5f * r * (1.0f + erff(r * 0.70710678118654752f));
}

extern "C" void kernel_launch(void* const* d_in, const int* in_sizes, int n_in,
                              void* d_out, int out_size, void* d_ws, size_t ws_size,
                              hipStream_t stream) {
    const float* cam_feat = (const float*)d_in[0];
    const float* intrins  = (const float*)d_in[1];
    const float* rots     = (const float*)d_in[2];
    const float* trans    = (const float*)d_in[3];
    const float* conv_w   = (const float*)d_in[4];
    float* out = (float*)d_out;
    float* ws  = (float*)d_ws;

    float* mats  = ws;                                          // 160 f
    float* uv    = ws + 160;                                    // NVOX*12 f
    unsigned short* featT = (unsigned short*)(uv + (size_t)NVOX*12);   // 4,300,800 bf16
    unsigned short* bevin = featT + (size_t)SNUM*HW*CNUM;       // 16,777,216 bf16
    unsigned short* w2    = bevin + (size_t)16384*1024;         // 1,179,648 bf16
    float* stats = (float*)(w2 + 9*128*1024);                   // 256 f
    // total ~50.8 MB

    hipLaunchKernelGGL(k_setup, dim3(1), dim3(64), 0, stream, intrins, rots, trans, mats);
    hipLaunchKernelGGL(k_tfeat, dim3(HW/32, CNUM/32, SNUM), dim3(32,8), 0, stream, cam_feat, featT);
    hipLaunchKernelGGL(k_geo, dim3(NVOX/256), dim3(256), 0, stream, mats, uv);
    hipLaunchKernelGGL(k_wprep, dim3((9*128*1024 + 255)/256), dim3(256), 0, stream, conv_w, w2);
    hipLaunchKernelGGL(k_sample, dim3(8192), dim3(256), 0, stream, featT, uv, bevin);
    hipLaunchKernelGGL(k_conv_mfma, dim3(128, 2), dim3(256), 0, stream, bevin, w2, out);
    hipLaunchKernelGGL(k_instnorm_stats, dim3(128), dim3(256), 0, stream, out, stats);
    hipLaunchKernelGGL(k_gelu, dim3(8192), dim3(256), 0, stream, out, stats);
}